// Round 8
// baseline (1036.439 us; speedup 1.0000x reference)
//
#include <hip/hip_runtime.h>
#include <hip/hip_bf16.h>
#include <hip/hip_fp16.h>

typedef unsigned short ushortT;
typedef _Float16 half8 __attribute__((ext_vector_type(8)));
typedef float f32x4 __attribute__((ext_vector_type(4)));

#define N_ROWS   32768
#define DIM      512
#define K_CODES  8192
#define BETA     0.01f

// d_out layout (floats): [quantized 16777216][loss 1][indices-as-float 32768]
#define LOSS_OFF 16777216
#define IDX_OFF  16777217

// d_out-as-scratch (floats offsets). Legal: vq_gather rewrites [0,16.7M) last.
#define SC_XH_F    0            // 32768*512 halves = 8M floats
#define SC_EH_F    8388608      // 8192*512 halves  = 2M floats
#define SC_GCODE_F 10485760     // 32768*16 u32
#define SC_GCNT_F  11010048     // 32768 u32

// d_ws layout (4-byte units): xx[32768] | idx[32768] | partial[8192] | cnt[1] | list[32768]
#define WS_XX_OFF     0
#define WS_IDX_OFF    32768
#define WS_PART_OFF   65536
#define WS_CNT_OFF    73728
#define WS_LIST_OFF   73729

#define FLT_BIG 3.402823466e+38f
#define W_ACC   0.08192f   // 1.6e-4 (s-domain window) * 512 (acc scale = 1024/2)
#define GCAP    16

typedef __attribute__((address_space(1))) const unsigned int GUI;
typedef __attribute__((address_space(3))) unsigned int LUI;
__device__ __forceinline__ void gload16(const void* g, void* l) {
    __builtin_amdgcn_global_load_lds((GUI*)g, (LUI*)l, 16, 0, 0);
}

// ---------------------------------------------------------------- prep
__global__ __launch_bounds__(256) void vq_prep(const float* __restrict__ x,
                                               const float* __restrict__ cb,
                                               ushortT* __restrict__ xh,
                                               ushortT* __restrict__ eh) {
    const size_t gid = (size_t)blockIdx.x * 256 + threadIdx.x;
    const size_t off8 = gid * 8;
    const float* src;
    ushortT* dst;
    float sc;
    if (off8 < 16777216UL) { src = x + off8; dst = xh + off8; sc = 1.0f; }
    else { size_t o = off8 - 16777216UL; src = cb + o; dst = eh + o; sc = 1024.0f; }
    float4 v0 = *reinterpret_cast<const float4*>(src);
    float4 v1 = *reinterpret_cast<const float4*>(src + 4);
    union { ushortT s[8]; uint4 v; } u;
    u.s[0] = __half_as_ushort(__float2half(v0.x * sc));
    u.s[1] = __half_as_ushort(__float2half(v0.y * sc));
    u.s[2] = __half_as_ushort(__float2half(v0.z * sc));
    u.s[3] = __half_as_ushort(__float2half(v0.w * sc));
    u.s[4] = __half_as_ushort(__float2half(v1.x * sc));
    u.s[5] = __half_as_ushort(__float2half(v1.y * sc));
    u.s[6] = __half_as_ushort(__float2half(v1.z * sc));
    u.s[7] = __half_as_ushort(__float2half(v1.w * sc));
    *reinterpret_cast<uint4*>(dst) = u.v;
}

// ---------------------------------------------------------------- kernel XX
// xx[n] replicating numpy pairwise_sum exactly (proven in round 3).
__global__ __launch_bounds__(256) void vq_xx_kernel(const float* __restrict__ x,
                                                    float* __restrict__ xx) {
    __shared__ float l[4][512];
    const int wave = threadIdx.x >> 6;
    const int lane = threadIdx.x & 63;
    const int row = blockIdx.x * 4 + wave;
    const float* xr = x + (size_t)row * DIM;
#pragma unroll
    for (int i = 0; i < 2; ++i) {
        float4 v = *reinterpret_cast<const float4*>(xr + lane * 8 + i * 4);
        float4 q = make_float4(v.x * v.x, v.y * v.y, v.z * v.z, v.w * v.w);
        *reinterpret_cast<float4*>(&l[wave][lane * 8 + i * 4]) = q;
    }
    __syncthreads();
    if (lane == 0) {
        float B[4];
#pragma unroll
        for (int q = 0; q < 4; ++q) {
            const float* a = &l[wave][q * 128];
            float r0 = a[0], r1 = a[1], r2 = a[2], r3 = a[3];
            float r4 = a[4], r5 = a[5], r6 = a[6], r7 = a[7];
            for (int i = 8; i < 128; i += 8) {
                r0 += a[i + 0]; r1 += a[i + 1]; r2 += a[i + 2]; r3 += a[i + 3];
                r4 += a[i + 4]; r5 += a[i + 5]; r6 += a[i + 6]; r7 += a[i + 7];
            }
            B[q] = ((r0 + r1) + (r2 + r3)) + ((r4 + r5) + (r6 + r7));
        }
        xx[row] = (B[0] + B[1]) + (B[2] + B[3]);
    }
}

// ---------------------------------------------------------------- kernel M
// fp16 MFMA candidate pass, K-SPLIT x2: grid 512, each block sweeps 4096 codes
// for 128 rows. BM=128 x BN=128, BKH=64, 8 waves (4 row-groups x 2 col-groups),
// wave tile 32x64 (mf2 x nf4). 2-buf LDS (64 KB, extras aliased into As[0])
// -> 2 blocks/CU, 16 waves/CU. Step loop unrolled x2 (compile-time buffers),
// counted vmcnt, raw barriers. Per-lane top-2(+tags)/top-3-value of raw acc
// (argmin s == argmax acc). Blocks merge candidates via global atomics.
#define BM 128
#define BN 128
#define BKH 64
#define KHALF 4096
#define NSTEP 256   // (KHALF/BN)=32 k0t * 8 kt
#define ABUF 8192   // halves per buffer (128*64)

__global__ __launch_bounds__(512, 4) void vq_margmin(
    const ushortT* __restrict__ xh, const ushortT* __restrict__ eh,
    unsigned* __restrict__ gCode, unsigned* __restrict__ gCnt,
    int* __restrict__ fixcnt, int* __restrict__ fixlist) {
    __shared__ ushortT As[2][ABUF];   // 32 KB
    __shared__ ushortT Bs[2][ABUF];   // 32 KB
    // post-loop extras aliased into As[0] (staging done by then):
    float* v1L        = (float*)&As[0][0];      // [128][2]  1024 B
    float* rowThr     = (float*)&As[0][512];    // [128]     512 B
    unsigned* candCnt = (unsigned*)&As[0][768]; // [128]     512 B
    int* flagL        = (int*)&As[0][1024];     // [128]     512 B
    ushortT* candList = &As[0][1280];           // [128][16] 4096 B

    const int t = threadIdx.x;
    const int l = t & 63;
    const int wid = t >> 6;
    const int wm = wid >> 1;      // 0..3 : 32-row region
    const int wn = wid & 1;       // 0..1 : 64-col region
    const int lr = l & 15;
    const int lg = l >> 4;
    const int rowBase = (blockIdx.x >> 1) * BM;
    const int kbase = (blockIdx.x & 1) * KHALF;

    // per-thread staging addresses (A: 2 chunks, B: 2 chunks of 16 B)
    const ushortT* aSrc0; const ushortT* aSrc1;
    const ushortT* bSrc0; const ushortT* bSrc1;
    int dOff0, dOff1;
    {
        int f0 = t, r0 = f0 >> 3, g0 = f0 & 7, gs0 = g0 ^ (r0 & 7);
        int f1 = t + 512, r1 = f1 >> 3, g1 = f1 & 7, gs1 = g1 ^ (r1 & 7);
        aSrc0 = xh + (size_t)(rowBase + r0) * DIM + gs0 * 8;
        aSrc1 = xh + (size_t)(rowBase + r1) * DIM + gs1 * 8;
        bSrc0 = eh + (size_t)(kbase + r0) * DIM + gs0 * 8;
        bSrc1 = eh + (size_t)(kbase + r1) * DIM + gs1 * 8;
        dOff0 = f0 * 8; dOff1 = f1 * 8;
    }
    // precomputed ds_read byte offsets (within one buffer)
    int offA[2][2], offB[4][2];
#pragma unroll
    for (int kk = 0; kk < 2; ++kk) {
#pragma unroll
        for (int mf = 0; mf < 2; ++mf) {
            int row = wm * 32 + mf * 16 + lr;
            int pg = (kk * 4 + lg) ^ (row & 7);
            offA[mf][kk] = row * 128 + pg * 16;
        }
#pragma unroll
        for (int nf = 0; nf < 4; ++nf) {
            int col = wn * 64 + nf * 16 + lr;
            int pg = (kk * 4 + lg) ^ (col & 7);
            offB[nf][kk] = col * 128 + pg * 16;
        }
    }

    float v1[2][4], v2m[2][4], v3m[2][4];
    int i1[2][4], i2[2][4];
#pragma unroll
    for (int mf = 0; mf < 2; ++mf)
#pragma unroll
        for (int rr = 0; rr < 4; ++rr) {
            v1[mf][rr] = -FLT_BIG; v2m[mf][rr] = -FLT_BIG; v3m[mf][rr] = -FLT_BIG;
            i1[mf][rr] = 0; i2[mf][rr] = 0;
        }

    f32x4 acc[2][4];

#define STAGE(stp, b) do {                                                     \
    int kt_ = ((stp) & 7) * BKH;                                               \
    size_t bAdd_ = (size_t)((stp) >> 3) * BN * DIM + kt_;                      \
    gload16(aSrc0 + kt_, &As[b][dOff0]);                                       \
    gload16(aSrc1 + kt_, &As[b][dOff1]);                                       \
    gload16(bSrc0 + bAdd_, &Bs[b][dOff0]);                                     \
    gload16(bSrc1 + bAdd_, &Bs[b][dOff1]);                                     \
} while (0)

#define COMPUTE(CUR) do {                                                      \
    _Pragma("unroll")                                                          \
    for (int kk = 0; kk < 2; ++kk) {                                           \
        half8 a0 = *reinterpret_cast<const half8*>((const char*)&As[CUR][0] + offA[0][kk]); \
        half8 a1 = *reinterpret_cast<const half8*>((const char*)&As[CUR][0] + offA[1][kk]); \
        half8 b0 = *reinterpret_cast<const half8*>((const char*)&Bs[CUR][0] + offB[0][kk]); \
        half8 b1 = *reinterpret_cast<const half8*>((const char*)&Bs[CUR][0] + offB[1][kk]); \
        half8 b2 = *reinterpret_cast<const half8*>((const char*)&Bs[CUR][0] + offB[2][kk]); \
        half8 b3 = *reinterpret_cast<const half8*>((const char*)&Bs[CUR][0] + offB[3][kk]); \
        acc[0][0] = __builtin_amdgcn_mfma_f32_16x16x32_f16(a0, b0, acc[0][0], 0, 0, 0); \
        acc[0][1] = __builtin_amdgcn_mfma_f32_16x16x32_f16(a0, b1, acc[0][1], 0, 0, 0); \
        acc[0][2] = __builtin_amdgcn_mfma_f32_16x16x32_f16(a0, b2, acc[0][2], 0, 0, 0); \
        acc[0][3] = __builtin_amdgcn_mfma_f32_16x16x32_f16(a0, b3, acc[0][3], 0, 0, 0); \
        acc[1][0] = __builtin_amdgcn_mfma_f32_16x16x32_f16(a1, b0, acc[1][0], 0, 0, 0); \
        acc[1][1] = __builtin_amdgcn_mfma_f32_16x16x32_f16(a1, b1, acc[1][1], 0, 0, 0); \
        acc[1][2] = __builtin_amdgcn_mfma_f32_16x16x32_f16(a1, b2, acc[1][2], 0, 0, 0); \
        acc[1][3] = __builtin_amdgcn_mfma_f32_16x16x32_f16(a1, b3, acc[1][3], 0, 0, 0); \
    }                                                                          \
} while (0)

#define EPILOGUE(k0t_) do {                                                    \
    _Pragma("unroll")                                                          \
    for (int mf = 0; mf < 2; ++mf) {                                           \
        _Pragma("unroll")                                                      \
        for (int nf = 0; nf < 4; ++nf) {                                       \
            const int tag = ((k0t_) << 2) | nf;                                \
            _Pragma("unroll")                                                  \
            for (int rr = 0; rr < 4; ++rr) {                                   \
                float s = acc[mf][nf][rr];                                     \
                bool g1 = s > v1[mf][rr];                                      \
                bool g2 = s > v2m[mf][rr];                                     \
                bool g3 = s > v3m[mf][rr];                                     \
                v3m[mf][rr] = g2 ? v2m[mf][rr] : (g3 ? s : v3m[mf][rr]);       \
                i2[mf][rr]  = g1 ? i1[mf][rr]  : (g2 ? tag : i2[mf][rr]);      \
                v2m[mf][rr] = g1 ? v1[mf][rr]  : (g2 ? s : v2m[mf][rr]);       \
                i1[mf][rr]  = g1 ? tag : i1[mf][rr];                           \
                v1[mf][rr]  = g1 ? s   : v1[mf][rr];                           \
            }                                                                  \
        }                                                                      \
    }                                                                          \
} while (0)

    STAGE(0, 0);
    for (int sp = 0; sp < NSTEP; sp += 2) {
        if ((sp & 7) == 0) {
#pragma unroll
            for (int mf = 0; mf < 2; ++mf)
#pragma unroll
                for (int nf = 0; nf < 4; ++nf)
                    acc[mf][nf] = (f32x4){0.f, 0.f, 0.f, 0.f};
        }
        // ---- even step: buffer 0
        STAGE(sp + 1, 1);
        asm volatile("s_waitcnt vmcnt(4)" ::: "memory");
        __builtin_amdgcn_sched_barrier(0);
        __builtin_amdgcn_s_barrier();
        COMPUTE(0);
        __builtin_amdgcn_s_barrier();
        // ---- odd step: buffer 1
        if (sp + 2 < NSTEP) {
            STAGE(sp + 2, 0);
            asm volatile("s_waitcnt vmcnt(4)" ::: "memory");
        } else {
            asm volatile("s_waitcnt vmcnt(0)" ::: "memory");
        }
        __builtin_amdgcn_sched_barrier(0);
        __builtin_amdgcn_s_barrier();
        COMPUTE(1);
        if ((sp & 7) == 6) EPILOGUE(sp >> 3);
        __builtin_amdgcn_s_barrier();
    }

    __syncthreads();   // all compute done before aliasing As[0]
    // ---- Phase A: in-wave (16 lr lanes) max per row
#pragma unroll
    for (int mf = 0; mf < 2; ++mf)
#pragma unroll
        for (int rr = 0; rr < 4; ++rr) {
            float v = v1[mf][rr];
            v = fmaxf(v, __shfl_xor(v, 1));
            v = fmaxf(v, __shfl_xor(v, 2));
            v = fmaxf(v, __shfl_xor(v, 4));
            v = fmaxf(v, __shfl_xor(v, 8));
            if (lr == 0) v1L[(wm * 32 + mf * 16 + lg * 4 + rr) * 2 + wn] = v;
        }
    __syncthreads();
    // ---- Phase B: per-row local threshold + init
    if (t < BM) {
        rowThr[t] = fmaxf(v1L[t * 2], v1L[t * 2 + 1]) - W_ACC;
        candCnt[t] = 0u;
        flagL[t] = 0;
    }
    __syncthreads();
    // ---- Phase C: lane-level candidate pushes (top-2 tags) + 3rd-value flag
#pragma unroll
    for (int mf = 0; mf < 2; ++mf)
#pragma unroll
        for (int rr = 0; rr < 4; ++rr) {
            const int row = wm * 32 + mf * 16 + lg * 4 + rr;
            const float thr = rowThr[row];
            if (v1[mf][rr] >= thr) {
                unsigned pos = atomicAdd(&candCnt[row], 1u);
                int tg = i1[mf][rr];
                int code = kbase + ((tg >> 2) << 7) + (wn << 6) + ((tg & 3) << 4) + lr;
                if (pos < GCAP) candList[row * GCAP + pos] = (ushortT)code;
                else flagL[row] = 1;
            }
            if (v2m[mf][rr] >= thr) {
                unsigned pos = atomicAdd(&candCnt[row], 1u);
                int tg = i2[mf][rr];
                int code = kbase + ((tg >> 2) << 7) + (wn << 6) + ((tg & 3) << 4) + lr;
                if (pos < GCAP) candList[row * GCAP + pos] = (ushortT)code;
                else flagL[row] = 1;
            }
            if (v3m[mf][rr] >= thr) flagL[row] = 1;
        }
    __syncthreads();
    // ---- Phase D: merge into global candidate list via atomics
    if (t < BM) {
        const int grow = rowBase + t;
        unsigned cc = candCnt[t];
        bool ovf = (flagL[t] != 0) || (cc > GCAP);
        if (!ovf) {
            for (unsigned j = 0; j < cc; ++j) {
                unsigned pos = atomicAdd(&gCnt[grow], 1u);
                if (pos < GCAP) gCode[(size_t)grow * GCAP + pos] = candList[t * GCAP + j];
                else ovf = true;
            }
        }
        if (ovf) {
            int p = atomicAdd(fixcnt, 1);
            fixlist[p] = grow;
        }
    }
#undef STAGE
#undef COMPUTE
#undef EPILOGUE
}

// ---------------------------------------------------------------- refine
// fp64-exact dots for each candidate, quantized compare s=fl32(xx-(f32)(2*dot)),
// first-index tie-break. One wave per row. Rows with over-full candidate lists
// are skipped (fixup overrides them later in the stream).
__global__ __launch_bounds__(256) void vq_refine(
    const float* __restrict__ x, const float* __restrict__ cb,
    const float* __restrict__ xx, const unsigned* __restrict__ gCode,
    const unsigned* __restrict__ gCnt, float* __restrict__ outIdxF,
    int* __restrict__ idxI) {
    const int wave = threadIdx.x >> 6;
    const int lane = threadIdx.x & 63;
    const int row = blockIdx.x * 4 + wave;
    const unsigned cc = gCnt[row];
    if (cc == 0u || cc > GCAP) return;   // fixup handles these rows
    const float* xr = x + (size_t)row * DIM;
    float4 xa = *reinterpret_cast<const float4*>(xr + lane * 8);
    float4 xb = *reinterpret_cast<const float4*>(xr + lane * 8 + 4);
    const float xxrow = xx[row];
    float best = FLT_BIG;
    int bi = 0x7fffffff;
    for (unsigned c = 0; c < cc; ++c) {
        int code = (int)gCode[(size_t)row * GCAP + c];
        const float* er = cb + (size_t)code * DIM;
        float4 ea = *reinterpret_cast<const float4*>(er + lane * 8);
        float4 eb = *reinterpret_cast<const float4*>(er + lane * 8 + 4);
        double p = (double)xa.x * ea.x + (double)xa.y * ea.y
                 + (double)xa.z * ea.z + (double)xa.w * ea.w
                 + (double)xb.x * eb.x + (double)xb.y * eb.y
                 + (double)xb.z * eb.z + (double)xb.w * eb.w;
#pragma unroll
        for (int off = 1; off < 64; off <<= 1) p += __shfl_xor(p, off);
        float sc = xxrow - (float)(2.0 * p);
        if (sc < best || (sc == best && code < bi)) { best = sc; bi = code; }
    }
    if (lane == 0) { idxI[row] = bi; outIdxF[row] = (float)bi; }
}

// ---------------------------------------------------------------- fixup
// Full 8192-code re-rank for flagged rows (expected ~0). Round-3 proven.
__global__ __launch_bounds__(256) void vq_fixup_kernel(
    const float* __restrict__ x, const float* __restrict__ cb,
    const float* __restrict__ xx, const int* __restrict__ cnt,
    const int* __restrict__ list, float* __restrict__ outIdxF,
    int* __restrict__ idxI) {
    __shared__ float xr[DIM];
    __shared__ float rv[256];
    __shared__ int ri[256];
    const int t = threadIdx.x;
    const int nflag = *cnt;
    for (int it = blockIdx.x; it < nflag; it += gridDim.x) {
        const int row = list[it];
        __syncthreads();
        xr[t] = x[(size_t)row * DIM + t];
        xr[t + 256] = x[(size_t)row * DIM + 256 + t];
        __syncthreads();
        const float xxrow = xx[row];
        float best = FLT_BIG;
        int bi = 0x7fffffff;
        for (int k = t; k < K_CODES; k += 256) {
            const float* er = cb + (size_t)k * DIM;
            double xe0 = 0.0, xe1 = 0.0, xe2d = 0.0, xe3 = 0.0;
            for (int d = 0; d < DIM; d += 4) {
                float4 ev = *reinterpret_cast<const float4*>(er + d);
                xe0 = fma((double)xr[d + 0], (double)ev.x, xe0);
                xe1 = fma((double)xr[d + 1], (double)ev.y, xe1);
                xe2d = fma((double)xr[d + 2], (double)ev.z, xe2d);
                xe3 = fma((double)xr[d + 3], (double)ev.w, xe3);
            }
            double xe = (xe0 + xe1) + (xe2d + xe3);
            float c = (float)(2.0 * xe);
            float s = xxrow - c;
            if (s < best) { best = s; bi = k; }
        }
        rv[t] = best; ri[t] = bi;
        __syncthreads();
        for (int off = 128; off > 0; off >>= 1) {
            if (t < off) {
                float ov = rv[t + off]; int oi = ri[t + off];
                if (ov < rv[t] || (ov == rv[t] && oi < ri[t])) { rv[t] = ov; ri[t] = oi; }
            }
            __syncthreads();
        }
        if (t == 0) {
            idxI[row] = ri[0];
            outIdxF[row] = (float)ri[0];
        }
    }
}

// ---------------------------------------------------------------- gather
__global__ __launch_bounds__(256) void vq_gather_kernel(
    const float* __restrict__ x, const float* __restrict__ cb,
    const int* __restrict__ idxI, float* __restrict__ outQ,
    float* __restrict__ partial) {
    const int wave = threadIdx.x >> 6;
    const int lane = threadIdx.x & 63;
    const int row = blockIdx.x * 4 + wave;
    const int code = idxI[row];
    const float* xr = x + (size_t)row * DIM;
    const float* er = cb + (size_t)code * DIM;
    float* qr = outQ + (size_t)row * DIM;
    float s = 0.f;
#pragma unroll
    for (int i = 0; i < 2; ++i) {
        int d = lane * 8 + i * 4;
        float4 xv = *reinterpret_cast<const float4*>(xr + d);
        float4 ev = *reinterpret_cast<const float4*>(er + d);
        float4 dv = make_float4(ev.x - xv.x, ev.y - xv.y, ev.z - xv.z, ev.w - xv.w);
        *reinterpret_cast<float4*>(qr + d) = ev;
        s += dv.x * dv.x + dv.y * dv.y + dv.z * dv.z + dv.w * dv.w;
    }
#pragma unroll
    for (int off = 32; off > 0; off >>= 1) s += __shfl_xor(s, off);
    __shared__ float ws4[4];
    if (lane == 0) ws4[wave] = s;
    __syncthreads();
    if (threadIdx.x == 0)
        partial[blockIdx.x] = (ws4[0] + ws4[1]) + (ws4[2] + ws4[3]);
}

// ---------------------------------------------------------------- loss
__global__ __launch_bounds__(256) void vq_loss_kernel(const float* __restrict__ partial,
                                                      float* __restrict__ outLoss) {
    float s = 0.f;
    for (int i = threadIdx.x; i < 8192; i += 256) s += partial[i];
    __shared__ float sm[256];
    sm[threadIdx.x] = s;
    __syncthreads();
    for (int off = 128; off > 0; off >>= 1) {
        if (threadIdx.x < off) sm[threadIdx.x] += sm[threadIdx.x + off];
        __syncthreads();
    }
    if (threadIdx.x == 0)
        outLoss[0] = sm[0] * (1.0f + BETA) / 16777216.0f;
}

// ---------------------------------------------------------------- launch
extern "C" void kernel_launch(void* const* d_in, const int* in_sizes, int n_in,
                              void* d_out, int out_size, void* d_ws, size_t ws_size,
                              hipStream_t stream) {
    const float* x = (const float*)d_in[0];   // [32768, 512]
    const float* cb = (const float*)d_in[1];  // [8192, 512]
    float* out = (float*)d_out;

    // d_out scratch (rewritten by gather at the end)
    ushortT* xh = (ushortT*)out;
    ushortT* eh = (ushortT*)(out + SC_EH_F);
    unsigned* gCode = (unsigned*)(out + SC_GCODE_F);
    unsigned* gCnt = (unsigned*)(out + SC_GCNT_F);

    float* xx = (float*)d_ws + WS_XX_OFF;
    int* idxI = (int*)d_ws + WS_IDX_OFF;
    float* partial = (float*)d_ws + WS_PART_OFF;
    int* fixcnt = (int*)d_ws + WS_CNT_OFF;
    int* fixlist = (int*)d_ws + WS_LIST_OFF;

    hipMemsetAsync(fixcnt, 0, sizeof(int), stream);
    hipMemsetAsync(gCnt, 0, N_ROWS * sizeof(unsigned), stream);
    hipLaunchKernelGGL(vq_prep, dim3(10240), dim3(256), 0, stream, x, cb, xh, eh);
    hipLaunchKernelGGL(vq_xx_kernel, dim3(N_ROWS / 4), dim3(256), 0, stream, x, xx);
    hipLaunchKernelGGL(vq_margmin, dim3((N_ROWS / BM) * 2), dim3(512), 0, stream,
                       xh, eh, gCode, gCnt, fixcnt, fixlist);
    hipLaunchKernelGGL(vq_refine, dim3(N_ROWS / 4), dim3(256), 0, stream,
                       x, cb, xx, gCode, gCnt, out + IDX_OFF, idxI);
    hipLaunchKernelGGL(vq_fixup_kernel, dim3(256), dim3(256), 0, stream,
                       x, cb, xx, fixcnt, fixlist, out + IDX_OFF, idxI);
    hipLaunchKernelGGL(vq_gather_kernel, dim3(N_ROWS / 4), dim3(256), 0, stream,
                       x, cb, idxI, out, partial);
    hipLaunchKernelGGL(vq_loss_kernel, dim3(1), dim3(256), 0, stream,
                       partial, out + LOSS_OFF);
}

// Round 10
// 553.878 us; speedup vs baseline: 1.8712x; 1.8712x over previous
//
#include <hip/hip_runtime.h>
#include <hip/hip_bf16.h>
#include <hip/hip_fp16.h>

typedef unsigned short ushortT;
typedef _Float16 half8 __attribute__((ext_vector_type(8)));
typedef float f32x4 __attribute__((ext_vector_type(4)));

#define N_ROWS   32768
#define DIM      512
#define K_CODES  8192
#define BETA     0.01f

// d_out layout (floats): [quantized 16777216][loss 1][indices-as-float 32768]
#define LOSS_OFF 16777216
#define IDX_OFF  16777217

// d_out-as-scratch (float offsets). Legal: vq_gather rewrites [0,16.7M) last.
// Audited map (all disjoint):
//   xh      [0,        8388608)   32768*512 halves
//   eh      [8388608,  10485760)  8192*512 halves
//   gCode   [10485760, 11010048)  32768*16 u32
//   gCnt    [11010048, 11042816)  32768 u32          <-- 32768, not 8192!
//   fixmin  [11042816, 11108352)  32768 u64 (8B-aligned: 11042816*4%8==0)
//   fixlist [11108352, 11173888)  65536 i32
#define SC_XH_F      0
#define SC_EH_F      8388608
#define SC_GCODE_F   10485760
#define SC_GCNT_F    11010048
#define SC_FIXMIN_F  11042816
#define SC_FIXLIST_F 11108352

// d_ws layout (4-byte units): xx[32768] | idx[32768] | partial[8192] | cnt[1]
#define WS_XX_OFF     0
#define WS_IDX_OFF    32768
#define WS_PART_OFF   65536
#define WS_CNT_OFF    73728

#define FLT_BIG 3.402823466e+38f
#define W_ACC   0.08192f   // 1.6e-4 (s-domain window) * 512 (acc scale = 1024/2)
#define GCAP    16

typedef __attribute__((address_space(1))) const unsigned int GUI;
typedef __attribute__((address_space(3))) unsigned int LUI;
__device__ __forceinline__ void gload16(const void* g, void* l) {
    __builtin_amdgcn_global_load_lds((GUI*)g, (LUI*)l, 16, 0, 0);
}

// ---------------------------------------------------------------- prep
__global__ __launch_bounds__(256) void vq_prep(const float* __restrict__ x,
                                               const float* __restrict__ cb,
                                               ushortT* __restrict__ xh,
                                               ushortT* __restrict__ eh) {
    const size_t gid = (size_t)blockIdx.x * 256 + threadIdx.x;
    const size_t off8 = gid * 8;
    const float* src;
    ushortT* dst;
    float sc;
    if (off8 < 16777216UL) { src = x + off8; dst = xh + off8; sc = 1.0f; }
    else { size_t o = off8 - 16777216UL; src = cb + o; dst = eh + o; sc = 1024.0f; }
    float4 v0 = *reinterpret_cast<const float4*>(src);
    float4 v1 = *reinterpret_cast<const float4*>(src + 4);
    union { ushortT s[8]; uint4 v; } u;
    u.s[0] = __half_as_ushort(__float2half(v0.x * sc));
    u.s[1] = __half_as_ushort(__float2half(v0.y * sc));
    u.s[2] = __half_as_ushort(__float2half(v0.z * sc));
    u.s[3] = __half_as_ushort(__float2half(v0.w * sc));
    u.s[4] = __half_as_ushort(__float2half(v1.x * sc));
    u.s[5] = __half_as_ushort(__float2half(v1.y * sc));
    u.s[6] = __half_as_ushort(__float2half(v1.z * sc));
    u.s[7] = __half_as_ushort(__float2half(v1.w * sc));
    *reinterpret_cast<uint4*>(dst) = u.v;
}

// ---------------------------------------------------------------- kernel XX
// xx[n] replicating numpy pairwise_sum exactly (proven in round 3).
__global__ __launch_bounds__(256) void vq_xx_kernel(const float* __restrict__ x,
                                                    float* __restrict__ xx) {
    __shared__ float l[4][512];
    const int wave = threadIdx.x >> 6;
    const int lane = threadIdx.x & 63;
    const int row = blockIdx.x * 4 + wave;
    const float* xr = x + (size_t)row * DIM;
#pragma unroll
    for (int i = 0; i < 2; ++i) {
        float4 v = *reinterpret_cast<const float4*>(xr + lane * 8 + i * 4);
        float4 q = make_float4(v.x * v.x, v.y * v.y, v.z * v.z, v.w * v.w);
        *reinterpret_cast<float4*>(&l[wave][lane * 8 + i * 4]) = q;
    }
    __syncthreads();
    if (lane == 0) {
        float B[4];
#pragma unroll
        for (int q = 0; q < 4; ++q) {
            const float* a = &l[wave][q * 128];
            float r0 = a[0], r1 = a[1], r2 = a[2], r3 = a[3];
            float r4 = a[4], r5 = a[5], r6 = a[6], r7 = a[7];
            for (int i = 8; i < 128; i += 8) {
                r0 += a[i + 0]; r1 += a[i + 1]; r2 += a[i + 2]; r3 += a[i + 3];
                r4 += a[i + 4]; r5 += a[i + 5]; r6 += a[i + 6]; r7 += a[i + 7];
            }
            B[q] = ((r0 + r1) + (r2 + r3)) + ((r4 + r5) + (r6 + r7));
        }
        xx[row] = (B[0] + B[1]) + (B[2] + B[3]);
    }
}

// ---------------------------------------------------------------- kernel M
// fp16 MFMA candidate pass, K-SPLIT x2 (unchanged from round 8).
#define BM 128
#define BN 128
#define BKH 64
#define KHALF 4096
#define NSTEP 256
#define ABUF 8192

__global__ __launch_bounds__(512, 4) void vq_margmin(
    const ushortT* __restrict__ xh, const ushortT* __restrict__ eh,
    unsigned* __restrict__ gCode, unsigned* __restrict__ gCnt,
    int* __restrict__ fixcnt, int* __restrict__ fixlist) {
    __shared__ ushortT As[2][ABUF];   // 32 KB
    __shared__ ushortT Bs[2][ABUF];   // 32 KB
    float* v1L        = (float*)&As[0][0];      // [128][2]
    float* rowThr     = (float*)&As[0][512];
    unsigned* candCnt = (unsigned*)&As[0][768];
    int* flagL        = (int*)&As[0][1024];
    ushortT* candList = &As[0][1280];           // [128][16]

    const int t = threadIdx.x;
    const int l = t & 63;
    const int wid = t >> 6;
    const int wm = wid >> 1;
    const int wn = wid & 1;
    const int lr = l & 15;
    const int lg = l >> 4;
    const int rowBase = (blockIdx.x >> 1) * BM;
    const int kbase = (blockIdx.x & 1) * KHALF;

    const ushortT* aSrc0; const ushortT* aSrc1;
    const ushortT* bSrc0; const ushortT* bSrc1;
    int dOff0, dOff1;
    {
        int f0 = t, r0 = f0 >> 3, g0 = f0 & 7, gs0 = g0 ^ (r0 & 7);
        int f1 = t + 512, r1 = f1 >> 3, g1 = f1 & 7, gs1 = g1 ^ (r1 & 7);
        aSrc0 = xh + (size_t)(rowBase + r0) * DIM + gs0 * 8;
        aSrc1 = xh + (size_t)(rowBase + r1) * DIM + gs1 * 8;
        bSrc0 = eh + (size_t)(kbase + r0) * DIM + gs0 * 8;
        bSrc1 = eh + (size_t)(kbase + r1) * DIM + gs1 * 8;
        dOff0 = f0 * 8; dOff1 = f1 * 8;
    }
    int offA[2][2], offB[4][2];
#pragma unroll
    for (int kk = 0; kk < 2; ++kk) {
#pragma unroll
        for (int mf = 0; mf < 2; ++mf) {
            int row = wm * 32 + mf * 16 + lr;
            int pg = (kk * 4 + lg) ^ (row & 7);
            offA[mf][kk] = row * 128 + pg * 16;
        }
#pragma unroll
        for (int nf = 0; nf < 4; ++nf) {
            int col = wn * 64 + nf * 16 + lr;
            int pg = (kk * 4 + lg) ^ (col & 7);
            offB[nf][kk] = col * 128 + pg * 16;
        }
    }

    float v1[2][4], v2m[2][4], v3m[2][4];
    int i1[2][4], i2[2][4];
#pragma unroll
    for (int mf = 0; mf < 2; ++mf)
#pragma unroll
        for (int rr = 0; rr < 4; ++rr) {
            v1[mf][rr] = -FLT_BIG; v2m[mf][rr] = -FLT_BIG; v3m[mf][rr] = -FLT_BIG;
            i1[mf][rr] = 0; i2[mf][rr] = 0;
        }

    f32x4 acc[2][4];

#define STAGE(stp, b) do {                                                     \
    int kt_ = ((stp) & 7) * BKH;                                               \
    size_t bAdd_ = (size_t)((stp) >> 3) * BN * DIM + kt_;                      \
    gload16(aSrc0 + kt_, &As[b][dOff0]);                                       \
    gload16(aSrc1 + kt_, &As[b][dOff1]);                                       \
    gload16(bSrc0 + bAdd_, &Bs[b][dOff0]);                                     \
    gload16(bSrc1 + bAdd_, &Bs[b][dOff1]);                                     \
} while (0)

#define COMPUTE(CUR) do {                                                      \
    _Pragma("unroll")                                                          \
    for (int kk = 0; kk < 2; ++kk) {                                           \
        half8 a0 = *reinterpret_cast<const half8*>((const char*)&As[CUR][0] + offA[0][kk]); \
        half8 a1 = *reinterpret_cast<const half8*>((const char*)&As[CUR][0] + offA[1][kk]); \
        half8 b0 = *reinterpret_cast<const half8*>((const char*)&Bs[CUR][0] + offB[0][kk]); \
        half8 b1 = *reinterpret_cast<const half8*>((const char*)&Bs[CUR][0] + offB[1][kk]); \
        half8 b2 = *reinterpret_cast<const half8*>((const char*)&Bs[CUR][0] + offB[2][kk]); \
        half8 b3 = *reinterpret_cast<const half8*>((const char*)&Bs[CUR][0] + offB[3][kk]); \
        acc[0][0] = __builtin_amdgcn_mfma_f32_16x16x32_f16(a0, b0, acc[0][0], 0, 0, 0); \
        acc[0][1] = __builtin_amdgcn_mfma_f32_16x16x32_f16(a0, b1, acc[0][1], 0, 0, 0); \
        acc[0][2] = __builtin_amdgcn_mfma_f32_16x16x32_f16(a0, b2, acc[0][2], 0, 0, 0); \
        acc[0][3] = __builtin_amdgcn_mfma_f32_16x16x32_f16(a0, b3, acc[0][3], 0, 0, 0); \
        acc[1][0] = __builtin_amdgcn_mfma_f32_16x16x32_f16(a1, b0, acc[1][0], 0, 0, 0); \
        acc[1][1] = __builtin_amdgcn_mfma_f32_16x16x32_f16(a1, b1, acc[1][1], 0, 0, 0); \
        acc[1][2] = __builtin_amdgcn_mfma_f32_16x16x32_f16(a1, b2, acc[1][2], 0, 0, 0); \
        acc[1][3] = __builtin_amdgcn_mfma_f32_16x16x32_f16(a1, b3, acc[1][3], 0, 0, 0); \
    }                                                                          \
} while (0)

#define EPILOGUE(k0t_) do {                                                    \
    _Pragma("unroll")                                                          \
    for (int mf = 0; mf < 2; ++mf) {                                           \
        _Pragma("unroll")                                                      \
        for (int nf = 0; nf < 4; ++nf) {                                       \
            const int tag = ((k0t_) << 2) | nf;                                \
            _Pragma("unroll")                                                  \
            for (int rr = 0; rr < 4; ++rr) {                                   \
                float s = acc[mf][nf][rr];                                     \
                bool g1 = s > v1[mf][rr];                                      \
                bool g2 = s > v2m[mf][rr];                                     \
                bool g3 = s > v3m[mf][rr];                                     \
                v3m[mf][rr] = g2 ? v2m[mf][rr] : (g3 ? s : v3m[mf][rr]);       \
                i2[mf][rr]  = g1 ? i1[mf][rr]  : (g2 ? tag : i2[mf][rr]);      \
                v2m[mf][rr] = g1 ? v1[mf][rr]  : (g2 ? s : v2m[mf][rr]);       \
                i1[mf][rr]  = g1 ? tag : i1[mf][rr];                           \
                v1[mf][rr]  = g1 ? s   : v1[mf][rr];                           \
            }                                                                  \
        }                                                                      \
    }                                                                          \
} while (0)

    STAGE(0, 0);
    for (int sp = 0; sp < NSTEP; sp += 2) {
        if ((sp & 7) == 0) {
#pragma unroll
            for (int mf = 0; mf < 2; ++mf)
#pragma unroll
                for (int nf = 0; nf < 4; ++nf)
                    acc[mf][nf] = (f32x4){0.f, 0.f, 0.f, 0.f};
        }
        STAGE(sp + 1, 1);
        asm volatile("s_waitcnt vmcnt(4)" ::: "memory");
        __builtin_amdgcn_sched_barrier(0);
        __builtin_amdgcn_s_barrier();
        COMPUTE(0);
        __builtin_amdgcn_s_barrier();
        if (sp + 2 < NSTEP) {
            STAGE(sp + 2, 0);
            asm volatile("s_waitcnt vmcnt(4)" ::: "memory");
        } else {
            asm volatile("s_waitcnt vmcnt(0)" ::: "memory");
        }
        __builtin_amdgcn_sched_barrier(0);
        __builtin_amdgcn_s_barrier();
        COMPUTE(1);
        if ((sp & 7) == 6) EPILOGUE(sp >> 3);
        __builtin_amdgcn_s_barrier();
    }

    __syncthreads();
#pragma unroll
    for (int mf = 0; mf < 2; ++mf)
#pragma unroll
        for (int rr = 0; rr < 4; ++rr) {
            float v = v1[mf][rr];
            v = fmaxf(v, __shfl_xor(v, 1));
            v = fmaxf(v, __shfl_xor(v, 2));
            v = fmaxf(v, __shfl_xor(v, 4));
            v = fmaxf(v, __shfl_xor(v, 8));
            if (lr == 0) v1L[(wm * 32 + mf * 16 + lg * 4 + rr) * 2 + wn] = v;
        }
    __syncthreads();
    if (t < BM) {
        rowThr[t] = fmaxf(v1L[t * 2], v1L[t * 2 + 1]) - W_ACC;
        candCnt[t] = 0u;
        flagL[t] = 0;
    }
    __syncthreads();
#pragma unroll
    for (int mf = 0; mf < 2; ++mf)
#pragma unroll
        for (int rr = 0; rr < 4; ++rr) {
            const int row = wm * 32 + mf * 16 + lg * 4 + rr;
            const float thr = rowThr[row];
            if (v1[mf][rr] >= thr) {
                unsigned pos = atomicAdd(&candCnt[row], 1u);
                int tg = i1[mf][rr];
                int code = kbase + ((tg >> 2) << 7) + (wn << 6) + ((tg & 3) << 4) + lr;
                if (pos < GCAP) candList[row * GCAP + pos] = (ushortT)code;
                else flagL[row] = 1;
            }
            if (v2m[mf][rr] >= thr) {
                unsigned pos = atomicAdd(&candCnt[row], 1u);
                int tg = i2[mf][rr];
                int code = kbase + ((tg >> 2) << 7) + (wn << 6) + ((tg & 3) << 4) + lr;
                if (pos < GCAP) candList[row * GCAP + pos] = (ushortT)code;
                else flagL[row] = 1;
            }
            if (v3m[mf][rr] >= thr) flagL[row] = 1;
        }
    __syncthreads();
    if (t < BM) {
        const int grow = rowBase + t;
        unsigned cc = candCnt[t];
        bool ovf = (flagL[t] != 0) || (cc > GCAP);
        if (!ovf) {
            for (unsigned j = 0; j < cc; ++j) {
                unsigned pos = atomicAdd(&gCnt[grow], 1u);
                if (pos < GCAP) gCode[(size_t)grow * GCAP + pos] = candList[t * GCAP + j];
                else ovf = true;
            }
        }
        if (ovf) {
            int p = atomicAdd(fixcnt, 1);
            fixlist[p] = grow;     // fixlist sized 65536: safe for 2 entries/row
        }
    }
#undef STAGE
#undef COMPUTE
#undef EPILOGUE
}

// ---------------------------------------------------------------- refine
__global__ __launch_bounds__(256) void vq_refine(
    const float* __restrict__ x, const float* __restrict__ cb,
    const float* __restrict__ xx, const unsigned* __restrict__ gCode,
    const unsigned* __restrict__ gCnt, float* __restrict__ outIdxF,
    int* __restrict__ idxI) {
    const int wave = threadIdx.x >> 6;
    const int lane = threadIdx.x & 63;
    const int row = blockIdx.x * 4 + wave;
    const unsigned cc = gCnt[row];
    if (cc == 0u || cc > GCAP) return;   // fixup overrides these rows later
    const float* xr = x + (size_t)row * DIM;
    float4 xa = *reinterpret_cast<const float4*>(xr + lane * 8);
    float4 xb = *reinterpret_cast<const float4*>(xr + lane * 8 + 4);
    const float xxrow = xx[row];
    float best = FLT_BIG;
    int bi = 0x7fffffff;
    for (unsigned c = 0; c < cc; ++c) {
        int code = (int)gCode[(size_t)row * GCAP + c];
        const float* er = cb + (size_t)code * DIM;
        float4 ea = *reinterpret_cast<const float4*>(er + lane * 8);
        float4 eb = *reinterpret_cast<const float4*>(er + lane * 8 + 4);
        double p = (double)xa.x * ea.x + (double)xa.y * ea.y
                 + (double)xa.z * ea.z + (double)xa.w * ea.w
                 + (double)xb.x * eb.x + (double)xb.y * eb.y
                 + (double)xb.z * eb.z + (double)xb.w * eb.w;
#pragma unroll
        for (int off = 1; off < 64; off <<= 1) p += __shfl_xor(p, off);
        float sc = xxrow - (float)(2.0 * p);
        if (sc < best || (sc == best && code < bi)) { best = sc; bi = code; }
    }
    if (lane == 0) { idxI[row] = bi; outIdxF[row] = (float)bi; }
}

// ---------------------------------------------------------------- fixup A
// Parallel exact re-rank of flagged rows: each WAVE handles one 64-code chunk
// (128 chunks/row), fixed 2048-block grid strides all (row,chunk) units.
// Key = (fl32-score bits << 32) | code: scores ~512 > 0 so float bits are
// order-monotone; u64 atomicMin = min score, then min index (ref tie-break).
__global__ __launch_bounds__(256) void vq_fixup_scan(
    const float* __restrict__ x, const float* __restrict__ cb,
    const float* __restrict__ xx, const int* __restrict__ cnt,
    const int* __restrict__ list, unsigned long long* __restrict__ fixmin) {
    const int nflag = *cnt;
    if (nflag == 0) return;
    const int gw = (blockIdx.x * 256 + threadIdx.x) >> 6;
    const int lane = threadIdx.x & 63;
    const int nwaves = gridDim.x * 4;
    const int totalUnits = nflag * 128;
    for (int u = gw; u < totalUnits; u += nwaves) {
        const int row = list[u >> 7];
        const int kb = (u & 127) * 64;
        const float* xr = x + (size_t)row * DIM;
        float4 xa = *reinterpret_cast<const float4*>(xr + lane * 8);
        float4 xb = *reinterpret_cast<const float4*>(xr + lane * 8 + 4);
        const float xxrow = xx[row];
        unsigned long long best = ~0ULL;
        for (int k = kb; k < kb + 64; ++k) {
            const float* er = cb + (size_t)k * DIM;
            float4 ea = *reinterpret_cast<const float4*>(er + lane * 8);
            float4 eb = *reinterpret_cast<const float4*>(er + lane * 8 + 4);
            double p = (double)xa.x * ea.x + (double)xa.y * ea.y
                     + (double)xa.z * ea.z + (double)xa.w * ea.w
                     + (double)xb.x * eb.x + (double)xb.y * eb.y
                     + (double)xb.z * eb.z + (double)xb.w * eb.w;
#pragma unroll
            for (int off = 1; off < 64; off <<= 1) p += __shfl_xor(p, off);
            float sc = xxrow - (float)(2.0 * p);
            unsigned long long key =
                ((unsigned long long)__float_as_uint(sc) << 32) | (unsigned)k;
            best = (key < best) ? key : best;
        }
        if (lane == 0) atomicMin(&fixmin[row], best);
    }
}

// ---------------------------------------------------------------- fixup B
__global__ __launch_bounds__(256) void vq_fixup_write(
    const int* __restrict__ cnt, const int* __restrict__ list,
    const unsigned long long* __restrict__ fixmin,
    float* __restrict__ outIdxF, int* __restrict__ idxI) {
    const int i = blockIdx.x * 256 + threadIdx.x;
    if (i >= *cnt) return;
    const int row = list[i];
    const int code = (int)(unsigned)(fixmin[row] & 0xFFFFFFFFULL);
    idxI[row] = code;
    outIdxF[row] = (float)code;
}

// ---------------------------------------------------------------- gather
__global__ __launch_bounds__(256) void vq_gather_kernel(
    const float* __restrict__ x, const float* __restrict__ cb,
    const int* __restrict__ idxI, float* __restrict__ outQ,
    float* __restrict__ partial) {
    const int wave = threadIdx.x >> 6;
    const int lane = threadIdx.x & 63;
    const int row = blockIdx.x * 4 + wave;
    const int code = idxI[row];
    const float* xr = x + (size_t)row * DIM;
    const float* er = cb + (size_t)code * DIM;
    float* qr = outQ + (size_t)row * DIM;
    float s = 0.f;
#pragma unroll
    for (int i = 0; i < 2; ++i) {
        int d = lane * 8 + i * 4;
        float4 xv = *reinterpret_cast<const float4*>(xr + d);
        float4 ev = *reinterpret_cast<const float4*>(er + d);
        float4 dv = make_float4(ev.x - xv.x, ev.y - xv.y, ev.z - xv.z, ev.w - xv.w);
        *reinterpret_cast<float4*>(qr + d) = ev;
        s += dv.x * dv.x + dv.y * dv.y + dv.z * dv.z + dv.w * dv.w;
    }
#pragma unroll
    for (int off = 32; off > 0; off >>= 1) s += __shfl_xor(s, off);
    __shared__ float ws4[4];
    if (lane == 0) ws4[wave] = s;
    __syncthreads();
    if (threadIdx.x == 0)
        partial[blockIdx.x] = (ws4[0] + ws4[1]) + (ws4[2] + ws4[3]);
}

// ---------------------------------------------------------------- loss
__global__ __launch_bounds__(256) void vq_loss_kernel(const float* __restrict__ partial,
                                                      float* __restrict__ outLoss) {
    float s = 0.f;
    for (int i = threadIdx.x; i < 8192; i += 256) s += partial[i];
    __shared__ float sm[256];
    sm[threadIdx.x] = s;
    __syncthreads();
    for (int off = 128; off > 0; off >>= 1) {
        if (threadIdx.x < off) sm[threadIdx.x] += sm[threadIdx.x + off];
        __syncthreads();
    }
    if (threadIdx.x == 0)
        outLoss[0] = sm[0] * (1.0f + BETA) / 16777216.0f;
}

// ---------------------------------------------------------------- launch
extern "C" void kernel_launch(void* const* d_in, const int* in_sizes, int n_in,
                              void* d_out, int out_size, void* d_ws, size_t ws_size,
                              hipStream_t stream) {
    const float* x = (const float*)d_in[0];   // [32768, 512]
    const float* cb = (const float*)d_in[1];  // [8192, 512]
    float* out = (float*)d_out;

    // d_out scratch (rewritten by gather at the end)
    ushortT* xh = (ushortT*)out;
    ushortT* eh = (ushortT*)(out + SC_EH_F);
    unsigned* gCode = (unsigned*)(out + SC_GCODE_F);
    unsigned* gCnt = (unsigned*)(out + SC_GCNT_F);
    unsigned long long* fixmin = (unsigned long long*)(out + SC_FIXMIN_F);
    int* fixlist = (int*)(out + SC_FIXLIST_F);

    float* xx = (float*)d_ws + WS_XX_OFF;
    int* idxI = (int*)d_ws + WS_IDX_OFF;
    float* partial = (float*)d_ws + WS_PART_OFF;
    int* fixcnt = (int*)d_ws + WS_CNT_OFF;

    hipMemsetAsync(fixcnt, 0, sizeof(int), stream);
    hipMemsetAsync(gCnt, 0, N_ROWS * sizeof(unsigned), stream);
    hipMemsetAsync(fixmin, 0xFF, N_ROWS * sizeof(unsigned long long), stream);
    hipLaunchKernelGGL(vq_prep, dim3(10240), dim3(256), 0, stream, x, cb, xh, eh);
    hipLaunchKernelGGL(vq_xx_kernel, dim3(N_ROWS / 4), dim3(256), 0, stream, x, xx);
    hipLaunchKernelGGL(vq_margmin, dim3((N_ROWS / BM) * 2), dim3(512), 0, stream,
                       xh, eh, gCode, gCnt, fixcnt, fixlist);
    hipLaunchKernelGGL(vq_refine, dim3(N_ROWS / 4), dim3(256), 0, stream,
                       x, cb, xx, gCode, gCnt, out + IDX_OFF, idxI);
    hipLaunchKernelGGL(vq_fixup_scan, dim3(2048), dim3(256), 0, stream,
                       x, cb, xx, fixcnt, fixlist, fixmin);
    hipLaunchKernelGGL(vq_fixup_write, dim3(256), dim3(256), 0, stream,
                       fixcnt, fixlist, fixmin, out + IDX_OFF, idxI);
    hipLaunchKernelGGL(vq_gather_kernel, dim3(N_ROWS / 4), dim3(256), 0, stream,
                       x, cb, idxI, out, partial);
    hipLaunchKernelGGL(vq_loss_kernel, dim3(1), dim3(256), 0, stream,
                       partial, out + LOSS_OFF);
}